// Round 5
// baseline (3645.601 us; speedup 1.0000x reference)
//
#include <hip/hip_runtime.h>
#include <math.h>

typedef unsigned short ushort;
typedef unsigned int uint;
typedef __attribute__((ext_vector_type(8))) short short8;
typedef __attribute__((ext_vector_type(4))) float f32x4;
typedef __attribute__((ext_vector_type(4))) ushort us4;

constexpr int BS = 2, C_IN = 8, CTX = 1024, TGT = 96;
constexpr int DM = 256, NH = 16, DFF = 1024, NL = 4;
constexpr int NF = 256, TOTAL = 320;
constexpr int NB = 16;
constexpr int DK = 16;
constexpr float EPS = 1e-5f;
constexpr float SCALE = 0.25f;
constexpr int KHEAD = DM * TOTAL;  // 81920
constexpr int M = NB * TOTAL;      // 5120
constexpr int SHM_U16 = 17664;     // 34.5 KB LDS union (max over phases)
constexpr int GRID_MEGA = 512;     // 2 blocks/CU guaranteed by __launch_bounds__(256,2)

__device__ __forceinline__ ushort f2b(float x) {
    uint u = __float_as_uint(x);
    u += 0x7fff + ((u >> 16) & 1);
    return (ushort)(u >> 16);
}
__device__ __forceinline__ float bu2f(ushort x) { return __uint_as_float(((uint)x) << 16); }
__device__ __forceinline__ uint pack2(float a, float b) { return (uint)f2b(a) | ((uint)f2b(b) << 16); }

typedef __attribute__((address_space(3))) uint lds_u32;
typedef const __attribute__((address_space(1))) uint glb_u32;
__device__ __forceinline__ void ldst16(const void* g, void* l) {
    __builtin_amdgcn_global_load_lds((glb_u32*)g, (lds_u32*)l, 16, 0, 0);
}

#define PIPE_BARRIER() asm volatile("s_waitcnt vmcnt(0)\n\ts_barrier" ::: "memory")

// software grid barrier: monotonic counter in workspace (zeroed by k_prep each launch).
// Safe because GRID_MEGA blocks are guaranteed co-resident (see launch_bounds math).
__device__ __forceinline__ void gsync(uint* bar, uint target) {
    __threadfence();                       // release this thread's writes to device scope
    __syncthreads();
    if (threadIdx.x == 0) {
        __hip_atomic_fetch_add(bar, 1u, __ATOMIC_ACQ_REL, __HIP_MEMORY_SCOPE_AGENT);
        while (__hip_atomic_load(bar, __ATOMIC_ACQUIRE, __HIP_MEMORY_SCOPE_AGENT) < target)
            __builtin_amdgcn_s_sleep(8);
    }
    __syncthreads();
    __threadfence();                       // acquire side for all threads
}

// ---------------- weight conversions + RevIN + out-init in ONE launch ----------------
__global__ void k_prep(const float* __restrict__ WQ, const float* __restrict__ WK,
                       const float* __restrict__ WV, const float* __restrict__ WO,
                       const float* __restrict__ F1, const float* __restrict__ F2,
                       const float* __restrict__ Wh,
                       ushort* __restrict__ Wtqkv, ushort* __restrict__ WtO,
                       ushort* __restrict__ Ft1, ushort* __restrict__ Ft2,
                       ushort* __restrict__ WhT2,
                       const float* __restrict__ z, const float* __restrict__ rw,
                       const float* __restrict__ rb, float* __restrict__ zn,
                       const float* __restrict__ bhv, float* __restrict__ outp,
                       float* __restrict__ scalef, uint* __restrict__ bar) {
    __shared__ ushort tile[32][33];
    __shared__ float rr1[16], rr2[16], bcast[2];
    int i = blockIdx.x;
    int tx = threadIdx.x, ty = threadIdx.y;
    if (i < 1024) {
        int zz = i >> 6, w = zz >> 2, l = zz & 3;
        const float* src = (w == 0 ? WQ : (w == 1 ? WK : (w == 2 ? WV : WO))) + l * 65536;
        ushort* dst = (w < 3) ? (Wtqkv + (size_t)l * 768 * 256 + w * 256 * 256)
                              : (WtO + (size_t)l * 65536);
        int c0 = (i & 7) * 32, r0 = ((i >> 3) & 7) * 32;
        tile[ty][tx] = f2b(src[(r0 + ty) * 256 + c0 + tx]);
        __syncthreads();
        dst[(c0 + ty) * 256 + r0 + tx] = tile[tx][ty];
    } else if (i < 2048) {
        int j = i - 1024, l = j >> 8;
        const float* src = F1 + (size_t)l * 262144;
        ushort* dst = Ft1 + (size_t)l * 262144;
        int c0 = (j & 31) * 32, r0 = ((j >> 5) & 7) * 32;
        tile[ty][tx] = f2b(src[(r0 + ty) * 1024 + c0 + tx]);
        __syncthreads();
        dst[(c0 + ty) * 256 + r0 + tx] = tile[tx][ty];
    } else if (i < 3072) {
        int j = i - 2048, l = j >> 8;
        const float* src = F2 + (size_t)l * 262144;
        ushort* dst = Ft2 + (size_t)l * 262144;
        int c0 = (j & 7) * 32, r0 = ((j >> 3) & 31) * 32;
        tile[ty][tx] = f2b(src[(r0 + ty) * 256 + c0 + tx]);
        __syncthreads();
        dst[(c0 + ty) * 1024 + r0 + tx] = tile[tx][ty];
    } else if (i < 10752) {
        int j = i - 3072;
        int t0 = (j % 3) * 32, rest = j / 3;
        int d0 = (rest & 7) * 32, pp = rest >> 3;
        tile[ty][tx] = f2b(Wh[((size_t)(d0 + ty) * 320 + pp) * 96 + t0 + tx]);
        __syncthreads();
        WhT2[(size_t)(t0 + ty) * KHEAD + pp * 256 + d0 + tx] = tile[tx][ty];
    } else {
        int bc = i - 10752;
        int tid = ty * 32 + tx;
        if (i == 10752 && tid == 0) *bar = 0;   // reset grid-barrier counter for k_mega
        float x = z[bc * CTX + tid];
        float s1 = x, s2 = x * x;
#pragma unroll
        for (int off = 1; off < 64; off <<= 1) {
            s1 += __shfl_xor(s1, off);
            s2 += __shfl_xor(s2, off);
        }
        if ((tid & 63) == 0) { rr1[tid >> 6] = s1; rr2[tid >> 6] = s2; }
        __syncthreads();
        if (tid == 0) {
            float a1 = 0.f, a2 = 0.f;
            for (int k = 0; k < 16; k++) { a1 += rr1[k]; a2 += rr2[k]; }
            float m = a1 * (1.0f / CTX);
            float var = a2 * (1.0f / CTX) - m * m;
            float sd = sqrtf(var + EPS);
            bcast[0] = m; bcast[1] = sd;
        }
        __syncthreads();
        float m = bcast[0], sd = bcast[1];
        int c = bc & 7;
        float w = rw[c], bb = rb[c];
        zn[bc * CTX + tid] = (x - m) / sd * w + bb;
        if (tid < TGT) outp[bc * TGT + tid] = (bhv[tid] - bb) / (w + EPS * EPS) * sd + m;
        if (tid == 0) scalef[bc] = sd / (w + EPS * EPS);
    }
}

// ---------------- phase bodies (verified in the round-2 multi-kernel build) ----------------

__device__ __forceinline__ void embed_body(const float* __restrict__ zn, const float* __restrict__ Wf,
                                           const float* __restrict__ bfv, const float* __restrict__ Wc,
                                           const float* __restrict__ bcv, const float* __restrict__ Wpos,
                                           ushort* __restrict__ u, int item) {
    int bc = item / TOTAL, p = item % TOTAL, d = threadIdx.x;
    float acc;
    if (p < NF) {
        acc = bfv[d];
        int base = p * 4;
#pragma unroll
        for (int i = 0; i < 8; i++) {
            int idx = min(base + i, CTX - 1);
            acc += zn[bc * CTX + idx] * Wf[i * DM + d];
        }
    } else {
        int pc = p - NF;
        acc = bcv[d];
        int base = pc * 16;
#pragma unroll
        for (int i = 0; i < 32; i++) {
            int idx = min(base + i, CTX - 1);
            acc += zn[bc * CTX + idx] * Wc[i * DM + d];
        }
    }
    acc += Wpos[p * DM + d];
    u[((size_t)bc * TOTAL + p) * DM + d] = f2b(acc);
}

// 64x64 GEMM tile, async LDS staging + XOR swizzle, 2-phase double buffer.
// shm layout (ushort idx): As0 [0,2048) As1 [2048,4096) Bs0 [4096,6144) Bs1 [6144,8192)
template <int GELU, int QKV>
__device__ __forceinline__ void gemm64_body(const ushort* __restrict__ A, const ushort* __restrict__ Wt,
                                            const float* __restrict__ b0, const float* __restrict__ b1,
                                            const float* __restrict__ b2, ushort* __restrict__ C,
                                            ushort* __restrict__ C2, int N, int K,
                                            int m0, int n0, ushort* shm) {
    int tid = threadIdx.x;
    int wave = tid >> 6, lane = tid & 63;
    int quad = lane >> 4, l16 = lane & 15;
    ushort* As[2] = { shm, shm + 2048 };
    ushort* Bs[2] = { shm + 4096, shm + 6144 };

    f32x4 acc[4];
#pragma unroll
    for (int nt = 0; nt < 4; nt++) acc[nt] = (f32x4){0.f, 0.f, 0.f, 0.f};

    int srow = wave * 16 + (lane >> 2);
    int sc = (lane & 3) ^ ((srow >> 1) & 3);
    const ushort* Ag = &A[(size_t)(m0 + srow) * K + sc * 8];
    const ushort* Bg = &Wt[(size_t)(n0 + srow) * K + sc * 8];
    int rchunk = (quad ^ ((l16 >> 1) & 3)) * 8;

    ldst16(Ag, As[0] + wave * 16 * 32);
    ldst16(Bg, Bs[0] + wave * 16 * 32);
    PIPE_BARRIER();

    int nstep = K >> 5;
    int cur = 0;
    for (int t = 0; t < nstep; t++) {
        if (t + 1 < nstep) {
            ldst16(Ag + (t + 1) * 32, As[cur ^ 1] + wave * 16 * 32);
            ldst16(Bg + (t + 1) * 32, Bs[cur ^ 1] + wave * 16 * 32);
        }
        short8 af = *(const short8*)&As[cur][(wave * 16 + l16) * 32 + rchunk];
#pragma unroll
        for (int nt = 0; nt < 4; nt++) {
            short8 bf = *(const short8*)&Bs[cur][(nt * 16 + l16) * 32 + rchunk];
            acc[nt] = __builtin_amdgcn_mfma_f32_16x16x32_bf16(af, bf, acc[nt], 0, 0, 0);
        }
        PIPE_BARRIER();
        cur ^= 1;
    }
#pragma unroll
    for (int nt = 0; nt < 4; nt++) {
        int col = n0 + nt * 16 + l16;
        float bi;
        if (QKV) {
            int bs = (n0 + nt * 16) >> 8;
            const float* bp = bs == 0 ? b0 : (bs == 1 ? b1 : b2);
            bi = bp[col & 255];
        } else {
            bi = b0[col];
        }
#pragma unroll
        for (int r = 0; r < 4; r++) {
            int rowm = m0 + wave * 16 + quad * 4 + r;
            float vv = acc[nt][r] + bi;
            if (GELU) vv = vv * 0.5f * (1.0f + erff(vv * 0.70710678118f));
            if (QKV) {
                int bs = col >> 8;
                ushort* dst = (bs == 2) ? (C2 + (size_t)rowm * DM)
                                        : (C + (size_t)bs * (M * DM) + (size_t)rowm * DM);
                dst[col & 255] = f2b(vv);
            } else {
                C[(size_t)rowm * N + col] = f2b(vv);
            }
        }
    }
}

// GEMM(16x256) + bias + residual + LayerNorm.
// shm layout: As0 [0,512) As1 [512,1024) Bs0 [1024,9216) Bs1 [9216,17408) ps [17408,17664)
__device__ __forceinline__ void ln16_body(const ushort* __restrict__ A, const ushort* __restrict__ Wt,
                                          const float* __restrict__ bias, const float* __restrict__ ls,
                                          const float* __restrict__ lb, ushort* __restrict__ u,
                                          int K, int m0, ushort* shm) {
    int tid = threadIdx.x;
    int wave = tid >> 6, lane = tid & 63;
    int quad = lane >> 4, l16 = lane & 15;
    ushort* As[2] = { shm, shm + 512 };
    ushort* Bs[2] = { shm + 1024, shm + 9216 };
    float* ps1 = (float*)(shm + 17408);
    float* ps2 = ps1 + 64;

    f32x4 acc[4];
#pragma unroll
    for (int nt = 0; nt < 4; nt++) acc[nt] = (f32x4){0.f, 0.f, 0.f, 0.f};

    int brow = wave * 16 + (lane >> 2);
    int bc_swz = (lane & 3) ^ ((brow >> 1) & 3);
    const ushort* Bg0 = &Wt[(size_t)brow * K + bc_swz * 8];
    int ar = lane >> 2;
    int ac = (lane & 3) ^ ((ar >> 1) & 3);
    const ushort* Ag = &A[(size_t)(m0 + ar) * K + ac * 8];
    int rchunk = (quad ^ ((l16 >> 1) & 3)) * 8;

    if (tid < 64) ldst16(Ag, As[0]);
#pragma unroll
    for (int i = 0; i < 4; i++)
        ldst16(Bg0 + (size_t)i * 64 * K, Bs[0] + (i * 64 + wave * 16) * 32);
    PIPE_BARRIER();

    int nstep = K >> 5;
    int cur = 0;
    for (int t = 0; t < nstep; t++) {
        if (t + 1 < nstep) {
            if (tid < 64) ldst16(Ag + (t + 1) * 32, As[cur ^ 1]);
#pragma unroll
            for (int i = 0; i < 4; i++)
                ldst16(Bg0 + (size_t)i * 64 * K + (t + 1) * 32, Bs[cur ^ 1] + (i * 64 + wave * 16) * 32);
        }
        short8 af = *(const short8*)&As[cur][l16 * 32 + rchunk];
#pragma unroll
        for (int nt = 0; nt < 4; nt++) {
            short8 bf = *(const short8*)&Bs[cur][(wave * 64 + nt * 16 + l16) * 32 + rchunk];
            acc[nt] = __builtin_amdgcn_mfma_f32_16x16x32_bf16(af, bf, acc[nt], 0, 0, 0);
        }
        PIPE_BARRIER();
        cur ^= 1;
    }
    float xv[4][4];
#pragma unroll
    for (int r = 0; r < 4; r++) {
        int rowg = m0 + quad * 4 + r;
        float s1 = 0.f, s2 = 0.f;
#pragma unroll
        for (int nt = 0; nt < 4; nt++) {
            int col = wave * 64 + nt * 16 + l16;
            float x = acc[nt][r] + bias[col] + bu2f(u[(size_t)rowg * DM + col]);
            xv[r][nt] = x; s1 += x; s2 += x * x;
        }
        s1 += __shfl_xor(s1, 1); s2 += __shfl_xor(s2, 1);
        s1 += __shfl_xor(s1, 2); s2 += __shfl_xor(s2, 2);
        s1 += __shfl_xor(s1, 4); s2 += __shfl_xor(s2, 4);
        s1 += __shfl_xor(s1, 8); s2 += __shfl_xor(s2, 8);
        if (l16 == 0) { ps1[(quad * 4 + r) * 4 + wave] = s1; ps2[(quad * 4 + r) * 4 + wave] = s2; }
    }
    __syncthreads();
#pragma unroll
    for (int r = 0; r < 4; r++) {
        int rowl = quad * 4 + r, rowg = m0 + rowl;
        float s1 = ps1[rowl * 4 + 0] + ps1[rowl * 4 + 1] + ps1[rowl * 4 + 2] + ps1[rowl * 4 + 3];
        float s2 = ps2[rowl * 4 + 0] + ps2[rowl * 4 + 1] + ps2[rowl * 4 + 2] + ps2[rowl * 4 + 3];
        float m = s1 * (1.0f / DM);
        float var = s2 * (1.0f / DM) - m * m;
        float rs = rsqrtf(var + EPS);
#pragma unroll
        for (int nt = 0; nt < 4; nt++) {
            int col = wave * 64 + nt * 16 + l16;
            u[(size_t)rowg * DM + col] = f2b((xv[r][nt] - m) * rs * ls[col] + lb[col]);
        }
    }
}

// fused attention with residual-score recompute; K double-buffered.
// shm layout: K0 [0,5120) K1 [5120,10240) V [10240,15360)
__device__ __forceinline__ void attn_body(const ushort* __restrict__ qk, const ushort* __restrict__ vm,
                                          ushort* __restrict__ ao, int nj, int bh, int i0, ushort* sh) {
    uint* sh32 = (uint*)sh;
    int b = bh >> 4, h = bh & 15;
    int t = threadIdx.x, wave = t >> 6, lane = t & 63, quad = lane >> 4, l16 = lane & 15;
    const short8 zero8 = (short8){0, 0, 0, 0, 0, 0, 0, 0};

    __syncthreads();   // guard LDS reuse from previous item/phase

    f32x4 acc[20];
#pragma unroll
    for (int nt = 0; nt < 20; nt++) acc[nt] = (f32x4){0.f, 0.f, 0.f, 0.f};

    for (int idx = t; idx < 320; idx += 256) {
        int jp = idx >> 1, dh = idx & 1;
        int j = jp * 2;
        uint4 a = *(const uint4*)&vm[((size_t)b * TOTAL + j) * DM + h * DK + dh * 8];
        uint4 bb = *(const uint4*)&vm[((size_t)b * TOTAL + j + 1) * DM + h * DK + dh * 8];
        const ushort* ap = (const ushort*)&a;
        const ushort* bp = (const ushort*)&bb;
        int jr = j & 31;
        int q = (jr & 15) >> 2, jj = ((jr >> 4) << 2) + (jr & 3);
        int base = 10240 + ((j >> 5) * 4 + q) * 128 + jj;
#pragma unroll
        for (int dd = 0; dd < 8; dd++) {
            int d = dh * 8 + dd;
            uint val = (uint)ap[dd] | ((uint)bp[dd] << 16);
            sh32[(base + d * 8) >> 1] = val;
        }
    }

    for (int jl = 0; jl < nj; jl++) {
        const ushort* qm = qk + (size_t)(2 * jl) * M * DM;
        const ushort* km = qm + (size_t)M * DM;
        int kb = (jl & 1) * 5120;
        for (int idx = t; idx < 640; idx += 256) {
            int j = idx >> 1, half = idx & 1;
            short8 kv = *(const short8*)&km[((size_t)b * TOTAL + j) * DM + h * DK + half * 8];
            int jt = j >> 4, jln = j & 15;
            *(short8*)&sh[kb + ((jt * 2 + half) * 16 + jln) * 8] = kv;
        }
        short8 qf = zero8;
        if (quad < 2) qf = *(const short8*)&qm[((size_t)b * TOTAL + i0 + wave * 16 + l16) * DM + h * DK + quad * 8];
        __syncthreads();
#pragma unroll
        for (int nt = 0; nt < 20; nt++) {
            short8 kf = *(const short8*)&sh[kb + ((nt * 2 + (quad & 1)) * 16 + l16) * 8];
            acc[nt] = __builtin_amdgcn_mfma_f32_16x16x32_bf16(kf, qf, acc[nt], 0, 0, 0);
        }
    }

    float mx = -1e30f;
#pragma unroll
    for (int nt = 0; nt < 20; nt++)
#pragma unroll
        for (int r = 0; r < 4; r++) { acc[nt][r] *= SCALE; mx = fmaxf(mx, acc[nt][r]); }
    mx = fmaxf(mx, __shfl_xor(mx, 16));
    mx = fmaxf(mx, __shfl_xor(mx, 32));
    float sum = 0.f;
#pragma unroll
    for (int nt = 0; nt < 20; nt++)
#pragma unroll
        for (int r = 0; r < 4; r++) { acc[nt][r] = __expf(acc[nt][r] - mx); sum += acc[nt][r]; }
    sum += __shfl_xor(sum, 16);
    sum += __shfl_xor(sum, 32);
    float inv = 1.f / sum;
#pragma unroll
    for (int nt = 0; nt < 20; nt++)
#pragma unroll
        for (int r = 0; r < 4; r++) acc[nt][r] *= inv;

    f32x4 oacc = (f32x4){0.f, 0.f, 0.f, 0.f};
#pragma unroll
    for (int jt2 = 0; jt2 < 10; jt2++) {
        short8 vt = *(const short8*)&sh[10240 + ((jt2 * 4 + quad) * 16 + l16) * 8];
        union { short8 v; uint u[4]; } pf;
        pf.u[0] = pack2(acc[2 * jt2][0], acc[2 * jt2][1]);
        pf.u[1] = pack2(acc[2 * jt2][2], acc[2 * jt2][3]);
        pf.u[2] = pack2(acc[2 * jt2 + 1][0], acc[2 * jt2 + 1][1]);
        pf.u[3] = pack2(acc[2 * jt2 + 1][2], acc[2 * jt2 + 1][3]);
        oacc = __builtin_amdgcn_mfma_f32_16x16x32_bf16(vt, pf.v, oacc, 0, 0, 0);
    }
    us4 ov4 = (us4){f2b(oacc[0]), f2b(oacc[1]), f2b(oacc[2]), f2b(oacc[3])};
    *(us4*)&ao[((size_t)b * TOTAL + i0 + wave * 16 + l16) * DM + h * DK + quad * 4] = ov4;
}

__device__ __forceinline__ void head_body(const ushort* __restrict__ u, const ushort* __restrict__ WhT2,
                                          const float* __restrict__ scalef, float* __restrict__ out,
                                          int item) {
    int t0 = (item % 6) * 16;
    int wave = threadIdx.x >> 6, lane = threadIdx.x & 63;
    int quad = lane >> 4, l16 = lane & 15;
    int chunk = (item / 6) * 4 + wave;
    int kbeg = chunk * 1024;
    f32x4 acc = (f32x4){0.f, 0.f, 0.f, 0.f};
    const ushort* za = &u[(size_t)l16 * KHEAD + quad * 8];
    const ushort* wb = &WhT2[(size_t)(t0 + l16) * KHEAD + quad * 8];
#pragma unroll 4
    for (int k = kbeg; k < kbeg + 1024; k += 32) {
        short8 af = *(const short8*)&za[k];
        short8 bf = *(const short8*)&wb[k];
        acc = __builtin_amdgcn_mfma_f32_16x16x32_bf16(af, bf, acc, 0, 0, 0);
    }
#pragma unroll
    for (int r = 0; r < 4; r++) {
        int bcr = quad * 4 + r;
        atomicAdd(&out[bcr * TGT + t0 + l16], acc[r] * scalef[bcr]);
    }
}

// ---------------- persistent mega-kernel: normal launch + software grid barrier ----------------
struct MegaArgs {
    const float* zn; const float* Wf; const float* bfv; const float* Wc; const float* bcv;
    const float* Wpos;
    ushort* u; ushort* qkbuf; ushort* vbuf; ushort* ax; ushort* hbuf;
    const ushort* Wtqkv; const ushort* WtO; const ushort* Ft1; const ushort* Ft2;
    const ushort* WhT2;
    const float* bQ; const float* bK; const float* bV; const float* bO;
    const float* ln1s; const float* ln1b; const float* c1; const float* c2;
    const float* ln2s; const float* ln2b; const float* scalef; float* out;
    uint* bar;
};

__global__ __launch_bounds__(256, 2) void k_mega(MegaArgs a) {
    __shared__ __align__(16) ushort shm[SHM_U16];
    int bid = blockIdx.x;
    const int G = GRID_MEGA;
    uint step = 0;

    for (int it = bid; it < NB * TOTAL; it += G)
        embed_body(a.zn, a.Wf, a.bfv, a.Wc, a.bcv, a.Wpos, a.u, it);
    gsync(a.bar, ++step * G);

    for (int l = 0; l < NL; l++) {
        for (int it = bid; it < 960; it += G)
            gemm64_body<0, 1>(a.u, a.Wtqkv + (size_t)l * 768 * 256, a.bQ + l * DM, a.bK + l * DM,
                              a.bV + l * DM, a.qkbuf + (size_t)l * 2 * M * DM, a.vbuf,
                              768, 256, (it / 12) * 64, (it % 12) * 64, shm);
        gsync(a.bar, ++step * G);
        for (int it = bid; it < 1280; it += G)
            attn_body(a.qkbuf, a.vbuf, a.ax, l + 1, it & 255, (it >> 8) * 64, shm);
        gsync(a.bar, ++step * G);
        for (int it = bid; it < 320; it += G)
            ln16_body(a.ax, a.WtO + (size_t)l * 65536, a.bO + l * DM, a.ln1s + l * DM,
                      a.ln1b + l * DM, a.u, 256, it * 16, shm);
        gsync(a.bar, ++step * G);
        for (int it = bid; it < 1280; it += G)
            gemm64_body<1, 0>(a.u, a.Ft1 + (size_t)l * 262144, a.c1 + l * DFF, a.c1, a.c1,
                              a.hbuf, a.hbuf, 1024, 256, (it / 16) * 64, (it % 16) * 64, shm);
        gsync(a.bar, ++step * G);
        for (int it = bid; it < 320; it += G)
            ln16_body(a.hbuf, a.Ft2 + (size_t)l * 262144, a.c2 + l * DM, a.ln2s + l * DM,
                      a.ln2b + l * DM, a.u, 1024, it * 16, shm);
        gsync(a.bar, ++step * G);
    }

    for (int it = bid; it < 120; it += G)
        head_body(a.u, a.WhT2, a.scalef, a.out, it);
}

extern "C" void kernel_launch(void* const* d_in, const int* in_sizes, int n_in,
                              void* d_out, int out_size, void* d_ws, size_t ws_size,
                              hipStream_t stream) {
    const float* z       = (const float*)d_in[0];
    const float* revin_w = (const float*)d_in[1];
    const float* revin_b = (const float*)d_in[2];
    const float* Wf      = (const float*)d_in[3];
    const float* bfv     = (const float*)d_in[4];
    const float* Wc      = (const float*)d_in[5];
    const float* bcv     = (const float*)d_in[6];
    const float* Wpos    = (const float*)d_in[7];
    const float* WQ      = (const float*)d_in[8];
    const float* bQ      = (const float*)d_in[9];
    const float* WK      = (const float*)d_in[10];
    const float* bK      = (const float*)d_in[11];
    const float* WV      = (const float*)d_in[12];
    const float* bV      = (const float*)d_in[13];
    const float* WO      = (const float*)d_in[14];
    const float* bO      = (const float*)d_in[15];
    const float* ln1s    = (const float*)d_in[16];
    const float* ln1b    = (const float*)d_in[17];
    const float* ln2s    = (const float*)d_in[18];
    const float* ln2b    = (const float*)d_in[19];
    const float* F1      = (const float*)d_in[20];
    const float* c1      = (const float*)d_in[21];
    const float* F2      = (const float*)d_in[22];
    const float* c2      = (const float*)d_in[23];
    const float* Wh      = (const float*)d_in[24];
    const float* bh      = (const float*)d_in[25];
    float* out = (float*)d_out;

    char* p = (char*)d_ws;
    float* scalef = (float*)p;   p += 16 * 4;
    uint* bar = (uint*)p;        p += 64;           // grid-barrier counter (own cacheline)
    p = (char*)(((size_t)p + 255) & ~255ull);
    float* zn = (float*)p;       p += NB * CTX * 4;
    ushort* u     = (ushort*)p;  p += (size_t)M * DM * 2;
    ushort* qkbuf = (ushort*)p;  p += (size_t)NL * 2 * M * DM * 2;   // per-layer [Q_l, K_l]
    ushort* vbuf  = (ushort*)p;  p += (size_t)M * DM * 2;
    ushort* ax    = (ushort*)p;  p += (size_t)M * DM * 2;
    ushort* hbuf  = (ushort*)p;  p += (size_t)M * DFF * 2;
    ushort* Wtqkv = (ushort*)p;  p += (size_t)NL * 768 * 256 * 2;
    ushort* WtO   = (ushort*)p;  p += (size_t)NL * 256 * 256 * 2;
    ushort* Ft1   = (ushort*)p;  p += (size_t)NL * 1024 * 256 * 2;
    ushort* Ft2   = (ushort*)p;  p += (size_t)NL * 256 * 1024 * 2;
    ushort* WhT2  = (ushort*)p;  p += (size_t)TGT * KHEAD * 2;

    k_prep<<<10768, dim3(32, 32), 0, stream>>>(WQ, WK, WV, WO, F1, F2, Wh,
                                               Wtqkv, WtO, Ft1, Ft2, WhT2,
                                               z, revin_w, revin_b, zn,
                                               bh, out, scalef, bar);

    MegaArgs a = { zn, Wf, bfv, Wc, bcv, Wpos, u, qkbuf, vbuf, ax, hbuf,
                   Wtqkv, WtO, Ft1, Ft2, WhT2, bQ, bK, bV, bO,
                   ln1s, ln1b, c1, c2, ln2s, ln2b, scalef, out, bar };
    k_mega<<<GRID_MEGA, 256, 0, stream>>>(a);
}

// Round 6
// 441.399 us; speedup vs baseline: 8.2592x; 8.2592x over previous
//
#include <hip/hip_runtime.h>
#include <math.h>

typedef unsigned short ushort;
typedef unsigned int uint;
typedef __attribute__((ext_vector_type(8))) short short8;
typedef __attribute__((ext_vector_type(4))) float f32x4;
typedef __attribute__((ext_vector_type(4))) ushort us4;

constexpr int BS = 2, C_IN = 8, CTX = 1024, TGT = 96;
constexpr int DM = 256, NH = 16, DFF = 1024, NL = 4;
constexpr int NF = 256, TOTAL = 320;
constexpr int NB = 16;
constexpr int DK = 16;
constexpr float EPS = 1e-5f;
constexpr float SCALE = 0.25f;
constexpr int KHEAD = DM * TOTAL;  // 81920
constexpr int M = NB * TOTAL;      // 5120

__device__ __forceinline__ ushort f2b(float x) {
    uint u = __float_as_uint(x);
    u += 0x7fff + ((u >> 16) & 1);
    return (ushort)(u >> 16);
}
__device__ __forceinline__ float bu2f(ushort x) { return __uint_as_float(((uint)x) << 16); }
__device__ __forceinline__ uint pack2(float a, float b) { return (uint)f2b(a) | ((uint)f2b(b) << 16); }

typedef __attribute__((address_space(3))) uint lds_u32;
typedef const __attribute__((address_space(1))) uint glb_u32;
__device__ __forceinline__ void ldst16(const void* g, void* l) {
    __builtin_amdgcn_global_load_lds((glb_u32*)g, (lds_u32*)l, 16, 0, 0);
}

#define PIPE_BARRIER() asm volatile("s_waitcnt vmcnt(0)\n\ts_barrier" ::: "memory")

// ---------------- prep v2: vectorized weight transposes + RevIN + embed + out-init ----------------
// grid = 3328 x 256 threads:
//   [0,256)    QKVO 64x64 transpose tiles
//   [256,512)  F1   64x64 tiles
//   [512,768)  F2   64x64 tiles
//   [768,2048) Wh   64(d)x96(t) tiles (per patch pp, d-quarter)
//   [2048,3328) embed: per (bc, 4-patch group); stats recomputed per block from z
__global__ __launch_bounds__(256) void k_prep(
        const float* __restrict__ WQ, const float* __restrict__ WK,
        const float* __restrict__ WV, const float* __restrict__ WO,
        const float* __restrict__ F1, const float* __restrict__ F2,
        const float* __restrict__ Wh,
        ushort* __restrict__ Wtqkv, ushort* __restrict__ WtO,
        ushort* __restrict__ Ft1, ushort* __restrict__ Ft2,
        ushort* __restrict__ WhT2,
        const float* __restrict__ z, const float* __restrict__ rw,
        const float* __restrict__ rb,
        const float* __restrict__ Wf, const float* __restrict__ bfv,
        const float* __restrict__ Wc, const float* __restrict__ bcv,
        const float* __restrict__ Wpos, ushort* __restrict__ u,
        const float* __restrict__ bhv, float* __restrict__ outp,
        float* __restrict__ scalef) {
    __shared__ __align__(16) ushort tile[64 * 98];
    __shared__ float szn[CTX];
    __shared__ float red1[4], red2[4];
    int i = blockIdx.x, tid = threadIdx.x;

    if (i < 768) {
        // 64x64 f32 -> bf16 transpose (pad 66 to dodge bank conflicts)
        const float* src; ushort* dst; int lsrc, ldst_, r0, c0;
        if (i < 256) {
            int mat = i >> 4, l = mat >> 2, w = mat & 3;
            src = (w == 0 ? WQ : (w == 1 ? WK : (w == 2 ? WV : WO))) + l * 65536;
            dst = (w < 3) ? (Wtqkv + (size_t)l * 768 * 256 + w * 65536)
                          : (WtO + (size_t)l * 65536);
            lsrc = 256; ldst_ = 256; r0 = ((i >> 2) & 3) * 64; c0 = (i & 3) * 64;
        } else if (i < 512) {
            int j = i - 256, l = j >> 6, t = j & 63;
            src = F1 + (size_t)l * 262144; dst = Ft1 + (size_t)l * 262144;
            lsrc = 1024; ldst_ = 256; r0 = (t >> 4) * 64; c0 = (t & 15) * 64;
        } else {
            int j = i - 512, l = j >> 6, t = j & 63;
            src = F2 + (size_t)l * 262144; dst = Ft2 + (size_t)l * 262144;
            lsrc = 256; ldst_ = 1024; r0 = (t >> 2) * 64; c0 = (t & 3) * 64;
        }
#pragma unroll
        for (int it = 0; it < 4; it++) {
            int fid = it * 256 + tid;
            int fr = fid >> 4, fc = fid & 15;
            f32x4 v = *(const f32x4*)&src[(size_t)(r0 + fr) * lsrc + c0 + fc * 4];
            ushort* tr = &tile[fr * 66];
            tr[fc * 4 + 0] = f2b(v[0]); tr[fc * 4 + 1] = f2b(v[1]);
            tr[fc * 4 + 2] = f2b(v[2]); tr[fc * 4 + 3] = f2b(v[3]);
        }
        __syncthreads();
#pragma unroll
        for (int it = 0; it < 4; it++) {
            int sid = it * 256 + tid;
            int cr = sid >> 4, cc = sid & 15;
            us4 v = (us4){ tile[(cc * 4 + 0) * 66 + cr], tile[(cc * 4 + 1) * 66 + cr],
                           tile[(cc * 4 + 2) * 66 + cr], tile[(cc * 4 + 3) * 66 + cr] };
            *(us4*)&dst[(size_t)(c0 + cr) * ldst_ + r0 + cc * 4] = v;
        }
    } else if (i < 2048) {
        // Wh: src[(d*320+p)*96 + t] -> WhT2[t*KHEAD + p*256 + d]; tile 64 d x 96 t
        int j = i - 768;
        int pp = j >> 2, d0 = (j & 3) * 64;
#pragma unroll
        for (int it = 0; it < 6; it++) {
            int fid = it * 256 + tid;          // 0..1535
            int fr = fid / 24, fc = fid % 24;  // fr: d idx, fc: t/4
            f32x4 v = *(const f32x4*)&Wh[((size_t)(d0 + fr) * 320 + pp) * 96 + fc * 4];
            ushort* tr = &tile[fr * 98];
            tr[fc * 4 + 0] = f2b(v[0]); tr[fc * 4 + 1] = f2b(v[1]);
            tr[fc * 4 + 2] = f2b(v[2]); tr[fc * 4 + 3] = f2b(v[3]);
        }
        __syncthreads();
#pragma unroll
        for (int it = 0; it < 6; it++) {
            int sid = it * 256 + tid;
            int tr = sid >> 4, dc = sid & 15;  // tr: t idx, dc: d/4
            us4 v = (us4){ tile[(dc * 4 + 0) * 98 + tr], tile[(dc * 4 + 1) * 98 + tr],
                           tile[(dc * 4 + 2) * 98 + tr], tile[(dc * 4 + 3) * 98 + tr] };
            *(us4*)&WhT2[(size_t)tr * KHEAD + pp * 256 + d0 + dc * 4] = v;
        }
    } else {
        // embed: block handles (bc, patches pb*4..pb*4+3); stats recomputed from z
        int j = i - 2048;
        int bc = j / 80, pb = j % 80;
        int wave = tid >> 6, lane = tid & 63;
        f32x4 zv = *(const f32x4*)&z[bc * CTX + tid * 4];
        float s1 = zv[0] + zv[1] + zv[2] + zv[3];
        float s2 = zv[0] * zv[0] + zv[1] * zv[1] + zv[2] * zv[2] + zv[3] * zv[3];
#pragma unroll
        for (int off = 1; off < 64; off <<= 1) {
            s1 += __shfl_xor(s1, off);
            s2 += __shfl_xor(s2, off);
        }
        if (lane == 0) { red1[wave] = s1; red2[wave] = s2; }
        __syncthreads();
        s1 = red1[0] + red1[1] + red1[2] + red1[3];
        s2 = red2[0] + red2[1] + red2[2] + red2[3];
        float m = s1 * (1.0f / CTX);
        float var = s2 * (1.0f / CTX) - m * m;
        float sd = sqrtf(var + EPS);
        int c = bc & 7;
        float w = rw[c], bb = rb[c];
        float inv_sd_w = w / sd;
#pragma unroll
        for (int k = 0; k < 4; k++) szn[tid * 4 + k] = (zv[k] - m) * inv_sd_w + bb;
        if (pb == 0) {   // out-init + scale factor once per bc
            if (tid < TGT) outp[bc * TGT + tid] = (bhv[tid] - bb) / (w + EPS * EPS) * sd + m;
            if (tid == 0) scalef[bc] = sd / (w + EPS * EPS);
        }
        __syncthreads();
#pragma unroll
        for (int pi = 0; pi < 4; pi++) {
            int p = pb * 4 + pi, d = tid;
            float acc;
            if (p < NF) {
                acc = bfv[d];
                int base = p * 4;
#pragma unroll
                for (int q = 0; q < 8; q++)
                    acc += szn[min(base + q, CTX - 1)] * Wf[q * DM + d];
            } else {
                acc = bcv[d];
                int base = (p - NF) * 16;
#pragma unroll
                for (int q = 0; q < 32; q++)
                    acc += szn[min(base + q, CTX - 1)] * Wc[q * DM + d];
            }
            acc += Wpos[p * DM + d];
            u[((size_t)bc * TOTAL + p) * DM + d] = f2b(acc);
        }
    }
}

// ---------------- bf16 MFMA GEMM, 64x64 tile, 2-phase double-buffered pipeline ----------------
template <int GELU, int QKV>
__global__ __launch_bounds__(256) void k_gemm_mfma(const ushort* __restrict__ A,
                                                   const ushort* __restrict__ Wt,
                                                   const float* __restrict__ b0,
                                                   const float* __restrict__ b1,
                                                   const float* __restrict__ b2,
                                                   ushort* __restrict__ C,
                                                   ushort* __restrict__ C2,
                                                   int Mm, int N, int K) {
    __shared__ ushort As[2][64][32];
    __shared__ ushort Bs[2][64][32];
    int tid = threadIdx.x;
    int wave = tid >> 6, lane = tid & 63;
    int quad = lane >> 4, l16 = lane & 15;
    int m0 = blockIdx.y * 64, n0 = blockIdx.x * 64;

    f32x4 acc[4];
#pragma unroll
    for (int nt = 0; nt < 4; nt++) acc[nt] = (f32x4){0.f, 0.f, 0.f, 0.f};

    int srow = wave * 16 + (lane >> 2);
    int sc = (lane & 3) ^ ((srow >> 1) & 3);
    const ushort* Ag = &A[(size_t)(m0 + srow) * K + sc * 8];
    const ushort* Bg = &Wt[(size_t)(n0 + srow) * K + sc * 8];
    int rchunk = (quad ^ ((l16 >> 1) & 3)) * 8;

    ldst16(Ag, &As[0][wave * 16][0]);
    ldst16(Bg, &Bs[0][wave * 16][0]);
    PIPE_BARRIER();

    int nstep = K >> 5;
    int cur = 0;
    for (int t = 0; t < nstep; t++) {
        if (t + 1 < nstep) {
            ldst16(Ag + (t + 1) * 32, &As[cur ^ 1][wave * 16][0]);
            ldst16(Bg + (t + 1) * 32, &Bs[cur ^ 1][wave * 16][0]);
        }
        short8 af = *(const short8*)&As[cur][wave * 16 + l16][rchunk];
#pragma unroll
        for (int nt = 0; nt < 4; nt++) {
            short8 bf = *(const short8*)&Bs[cur][nt * 16 + l16][rchunk];
            acc[nt] = __builtin_amdgcn_mfma_f32_16x16x32_bf16(af, bf, acc[nt], 0, 0, 0);
        }
        PIPE_BARRIER();
        cur ^= 1;
    }
#pragma unroll
    for (int nt = 0; nt < 4; nt++) {
        int col = n0 + nt * 16 + l16;
        float bi;
        if (QKV) {
            int bs = (n0 + nt * 16) >> 8;
            const float* bp = bs == 0 ? b0 : (bs == 1 ? b1 : b2);
            bi = bp[col & 255];
        } else {
            bi = b0[col];
        }
#pragma unroll
        for (int r = 0; r < 4; r++) {
            int rowm = m0 + wave * 16 + quad * 4 + r;
            float vv = acc[nt][r] + bi;
            if (GELU) vv = vv * 0.5f * (1.0f + erff(vv * 0.70710678118f));
            if (QKV) {
                int bs = col >> 8;
                ushort* dst = (bs == 2) ? (C2 + (size_t)rowm * DM)
                                        : (C + (size_t)bs * (M * DM) + (size_t)rowm * DM);
                dst[col & 255] = f2b(vv);
            } else {
                C[(size_t)rowm * N + col] = f2b(vv);
            }
        }
    }
}

// ---------------- GEMM(16x256) + bias + residual + LayerNorm, 2-phase pipelined ----------------
__global__ __launch_bounds__(256) void k_gemm_ln16(const ushort* __restrict__ A,
                                                   const ushort* __restrict__ Wt,
                                                   const float* __restrict__ bias,
                                                   const float* __restrict__ ls,
                                                   const float* __restrict__ lb,
                                                   ushort* __restrict__ u, int K) {
    __shared__ ushort As[2][16][32];
    __shared__ ushort Bs[2][256][32];
    __shared__ float ps1[16][4], ps2[16][4];
    int tid = threadIdx.x;
    int wave = tid >> 6, lane = tid & 63;
    int quad = lane >> 4, l16 = lane & 15;
    int m0 = blockIdx.x * 16;

    f32x4 acc[4];
#pragma unroll
    for (int nt = 0; nt < 4; nt++) acc[nt] = (f32x4){0.f, 0.f, 0.f, 0.f};

    int brow = wave * 16 + (lane >> 2);
    int bc_swz = (lane & 3) ^ ((brow >> 1) & 3);
    const ushort* Bg0 = &Wt[(size_t)brow * K + bc_swz * 8];
    int ar = lane >> 2;
    int ac = (lane & 3) ^ ((ar >> 1) & 3);
    const ushort* Ag = &A[(size_t)(m0 + ar) * K + ac * 8];
    int rchunk = (quad ^ ((l16 >> 1) & 3)) * 8;

    if (tid < 64) ldst16(Ag, &As[0][0][0]);
#pragma unroll
    for (int i = 0; i < 4; i++)
        ldst16(Bg0 + (size_t)i * 64 * K, &Bs[0][i * 64 + wave * 16][0]);
    PIPE_BARRIER();

    int nstep = K >> 5;
    int cur = 0;
    for (int t = 0; t < nstep; t++) {
        if (t + 1 < nstep) {
            if (tid < 64) ldst16(Ag + (t + 1) * 32, &As[cur ^ 1][0][0]);
#pragma unroll
            for (int i = 0; i < 4; i++)
                ldst16(Bg0 + (size_t)i * 64 * K + (t + 1) * 32, &Bs[cur ^ 1][i * 64 + wave * 16][0]);
        }
        short8 af = *(const short8*)&As[cur][l16][rchunk];
#pragma unroll
        for (int nt = 0; nt < 4; nt++) {
            short8 bf = *(const short8*)&Bs[cur][wave * 64 + nt * 16 + l16][rchunk];
            acc[nt] = __builtin_amdgcn_mfma_f32_16x16x32_bf16(af, bf, acc[nt], 0, 0, 0);
        }
        PIPE_BARRIER();
        cur ^= 1;
    }
    float xv[4][4];
#pragma unroll
    for (int r = 0; r < 4; r++) {
        int rowg = m0 + quad * 4 + r;
        float s1 = 0.f, s2 = 0.f;
#pragma unroll
        for (int nt = 0; nt < 4; nt++) {
            int col = wave * 64 + nt * 16 + l16;
            float x = acc[nt][r] + bias[col] + bu2f(u[(size_t)rowg * DM + col]);
            xv[r][nt] = x; s1 += x; s2 += x * x;
        }
        s1 += __shfl_xor(s1, 1); s2 += __shfl_xor(s2, 1);
        s1 += __shfl_xor(s1, 2); s2 += __shfl_xor(s2, 2);
        s1 += __shfl_xor(s1, 4); s2 += __shfl_xor(s2, 4);
        s1 += __shfl_xor(s1, 8); s2 += __shfl_xor(s2, 8);
        if (l16 == 0) { ps1[quad * 4 + r][wave] = s1; ps2[quad * 4 + r][wave] = s2; }
    }
    __syncthreads();
#pragma unroll
    for (int r = 0; r < 4; r++) {
        int rowl = quad * 4 + r, rowg = m0 + rowl;
        float s1 = ps1[rowl][0] + ps1[rowl][1] + ps1[rowl][2] + ps1[rowl][3];
        float s2 = ps2[rowl][0] + ps2[rowl][1] + ps2[rowl][2] + ps2[rowl][3];
        float m = s1 * (1.0f / DM);
        float var = s2 * (1.0f / DM) - m * m;
        float rs = rsqrtf(var + EPS);
#pragma unroll
        for (int nt = 0; nt < 4; nt++) {
            int col = wave * 64 + nt * 16 + l16;
            u[(size_t)rowg * DM + col] = f2b((xv[r][nt] - m) * rs * ls[col] + lb[col]);
        }
    }
}

// ---------------- MFMA fused attention: residual scores recomputed; K double-buffered ----------------
__global__ __launch_bounds__(256, 4) void k_attn(const ushort* __restrict__ qk, const ushort* __restrict__ vm,
                                                 ushort* __restrict__ ao, int nj) {
    __shared__ ushort sh[15360];
    uint* sh32 = (uint*)sh;
    int bh = blockIdx.x, b = bh >> 4, h = bh & 15;
    int i0 = blockIdx.y * 64;
    int t = threadIdx.x, wave = t >> 6, lane = t & 63, quad = lane >> 4, l16 = lane & 15;
    const short8 zero8 = (short8){0, 0, 0, 0, 0, 0, 0, 0};

    f32x4 acc[20];
#pragma unroll
    for (int nt = 0; nt < 20; nt++) acc[nt] = (f32x4){0.f, 0.f, 0.f, 0.f};

    for (int idx = t; idx < 320; idx += 256) {
        int jp = idx >> 1, dh = idx & 1;
        int j = jp * 2;
        uint4 a = *(const uint4*)&vm[((size_t)b * TOTAL + j) * DM + h * DK + dh * 8];
        uint4 bb = *(const uint4*)&vm[((size_t)b * TOTAL + j + 1) * DM + h * DK + dh * 8];
        const ushort* ap = (const ushort*)&a;
        const ushort* bp = (const ushort*)&bb;
        int jr = j & 31;
        int q = (jr & 15) >> 2, jj = ((jr >> 4) << 2) + (jr & 3);
        int base = 10240 + ((j >> 5) * 4 + q) * 128 + jj;
#pragma unroll
        for (int dd = 0; dd < 8; dd++) {
            int d = dh * 8 + dd;
            uint val = (uint)ap[dd] | ((uint)bp[dd] << 16);
            sh32[(base + d * 8) >> 1] = val;
        }
    }

    for (int jl = 0; jl < nj; jl++) {
        const ushort* qm = qk + (size_t)(2 * jl) * M * DM;
        const ushort* km = qm + (size_t)M * DM;
        int kb = (jl & 1) * 5120;
        for (int idx = t; idx < 640; idx += 256) {
            int j = idx >> 1, half = idx & 1;
            short8 kv = *(const short8*)&km[((size_t)b * TOTAL + j) * DM + h * DK + half * 8];
            int jt = j >> 4, jln = j & 15;
            *(short8*)&sh[kb + ((jt * 2 + half) * 16 + jln) * 8] = kv;
        }
        short8 qf = zero8;
        if (quad < 2) qf = *(const short8*)&qm[((size_t)b * TOTAL + i0 + wave * 16 + l16) * DM + h * DK + quad * 8];
        __syncthreads();
#pragma unroll
        for (int nt = 0; nt < 20; nt++) {
            short8 kf = *(const short8*)&sh[kb + ((nt * 2 + (quad & 1)) * 16 + l16) * 8];
            acc[nt] = __builtin_amdgcn_mfma_f32_16x16x32_bf16(kf, qf, acc[nt], 0, 0, 0);
        }
    }

    float mx = -1e30f;
#pragma unroll
    for (int nt = 0; nt < 20; nt++)
#pragma unroll
        for (int r = 0; r < 4; r++) { acc[nt][r] *= SCALE; mx = fmaxf(mx, acc[nt][r]); }
    mx = fmaxf(mx, __shfl_xor(mx, 16));
    mx = fmaxf(mx, __shfl_xor(mx, 32));
    float sum = 0.f;
#pragma unroll
    for (int nt = 0; nt < 20; nt++)
#pragma unroll
        for (int r = 0; r < 4; r++) { acc[nt][r] = __expf(acc[nt][r] - mx); sum += acc[nt][r]; }
    sum += __shfl_xor(sum, 16);
    sum += __shfl_xor(sum, 32);
    float inv = 1.f / sum;
#pragma unroll
    for (int nt = 0; nt < 20; nt++)
#pragma unroll
        for (int r = 0; r < 4; r++) acc[nt][r] *= inv;

    f32x4 oacc = (f32x4){0.f, 0.f, 0.f, 0.f};
#pragma unroll
    for (int jt2 = 0; jt2 < 10; jt2++) {
        short8 vt = *(const short8*)&sh[10240 + ((jt2 * 4 + quad) * 16 + l16) * 8];
        union { short8 v; uint u[4]; } pf;
        pf.u[0] = pack2(acc[2 * jt2][0], acc[2 * jt2][1]);
        pf.u[1] = pack2(acc[2 * jt2][2], acc[2 * jt2][3]);
        pf.u[2] = pack2(acc[2 * jt2 + 1][0], acc[2 * jt2 + 1][1]);
        pf.u[3] = pack2(acc[2 * jt2 + 1][2], acc[2 * jt2 + 1][3]);
        oacc = __builtin_amdgcn_mfma_f32_16x16x32_bf16(vt, pf.v, oacc, 0, 0, 0);
    }
    us4 ov4 = (us4){f2b(oacc[0]), f2b(oacc[1]), f2b(oacc[2]), f2b(oacc[3])};
    *(us4*)&ao[((size_t)b * TOTAL + i0 + wave * 16 + l16) * DM + h * DK + quad * 4] = ov4;
}

// ---------------- head GEMM: MFMA split-K, atomic accumulate into pre-initialized out ----------------
__global__ __launch_bounds__(256) void k_head(const ushort* __restrict__ u, const ushort* __restrict__ WhT2,
                                              const float* __restrict__ scalef, float* __restrict__ out) {
    int t0 = blockIdx.x * 16;
    int wave = threadIdx.x >> 6, lane = threadIdx.x & 63;
    int quad = lane >> 4, l16 = lane & 15;
    int chunk = blockIdx.y * 4 + wave;
    int kbeg = chunk * 1024;
    f32x4 acc = (f32x4){0.f, 0.f, 0.f, 0.f};
    const ushort* za = &u[(size_t)l16 * KHEAD + quad * 8];
    const ushort* wb = &WhT2[(size_t)(t0 + l16) * KHEAD + quad * 8];
#pragma unroll 4
    for (int k = kbeg; k < kbeg + 1024; k += 32) {
        short8 af = *(const short8*)&za[k];
        short8 bf = *(const short8*)&wb[k];
        acc = __builtin_amdgcn_mfma_f32_16x16x32_bf16(af, bf, acc, 0, 0, 0);
    }
#pragma unroll
    for (int r = 0; r < 4; r++) {
        int bcr = quad * 4 + r;
        atomicAdd(&out[bcr * TGT + t0 + l16], acc[r] * scalef[bcr]);
    }
}

extern "C" void kernel_launch(void* const* d_in, const int* in_sizes, int n_in,
                              void* d_out, int out_size, void* d_ws, size_t ws_size,
                              hipStream_t stream) {
    const float* z       = (const float*)d_in[0];
    const float* revin_w = (const float*)d_in[1];
    const float* revin_b = (const float*)d_in[2];
    const float* Wf      = (const float*)d_in[3];
    const float* bfv     = (const float*)d_in[4];
    const float* Wc      = (const float*)d_in[5];
    const float* bcv     = (const float*)d_in[6];
    const float* Wpos    = (const float*)d_in[7];
    const float* WQ      = (const float*)d_in[8];
    const float* bQ      = (const float*)d_in[9];
    const float* WK      = (const float*)d_in[10];
    const float* bK      = (const float*)d_in[11];
    const float* WV      = (const float*)d_in[12];
    const float* bV      = (const float*)d_in[13];
    const float* WO      = (const float*)d_in[14];
    const float* bO      = (const float*)d_in[15];
    const float* ln1s    = (const float*)d_in[16];
    const float* ln1b    = (const float*)d_in[17];
    const float* ln2s    = (const float*)d_in[18];
    const float* ln2b    = (const float*)d_in[19];
    const float* F1      = (const float*)d_in[20];
    const float* c1      = (const float*)d_in[21];
    const float* F2      = (const float*)d_in[22];
    const float* c2      = (const float*)d_in[23];
    const float* Wh      = (const float*)d_in[24];
    const float* bh      = (const float*)d_in[25];
    float* out = (float*)d_out;

    char* p = (char*)d_ws;
    float* scalef = (float*)p;   p += 16 * 4;
    p = (char*)(((size_t)p + 255) & ~255ull);
    ushort* u     = (ushort*)p;  p += (size_t)M * DM * 2;
    ushort* qkbuf = (ushort*)p;  p += (size_t)NL * 2 * M * DM * 2;   // per-layer [Q_l, K_l]
    ushort* vbuf  = (ushort*)p;  p += (size_t)M * DM * 2;
    ushort* ax    = (ushort*)p;  p += (size_t)M * DM * 2;
    ushort* hbuf  = (ushort*)p;  p += (size_t)M * DFF * 2;
    ushort* Wtqkv = (ushort*)p;  p += (size_t)NL * 768 * 256 * 2;
    ushort* WtO   = (ushort*)p;  p += (size_t)NL * 256 * 256 * 2;
    ushort* Ft1   = (ushort*)p;  p += (size_t)NL * 1024 * 256 * 2;
    ushort* Ft2   = (ushort*)p;  p += (size_t)NL * 256 * 1024 * 2;
    ushort* WhT2  = (ushort*)p;  p += (size_t)TGT * KHEAD * 2;

    k_prep<<<3328, 256, 0, stream>>>(WQ, WK, WV, WO, F1, F2, Wh,
                                     Wtqkv, WtO, Ft1, Ft2, WhT2,
                                     z, revin_w, revin_b,
                                     Wf, bfv, Wc, bcv, Wpos, u,
                                     bh, out, scalef);

    for (int l = 0; l < NL; l++) {
        k_gemm_mfma<0, 1><<<dim3(12, 80), 256, 0, stream>>>(
            u, Wtqkv + (size_t)l * 768 * 256, bQ + l * DM, bK + l * DM, bV + l * DM,
            qkbuf + (size_t)l * 2 * M * DM, vbuf, M, 768, 256);
        k_attn<<<dim3(NB * NH, 5), 256, 0, stream>>>(qkbuf, vbuf, ax, l + 1);
        k_gemm_ln16<<<M / 16, 256, 0, stream>>>(
            ax, WtO + (size_t)l * 65536, bO + l * DM, ln1s + l * DM, ln1b + l * DM, u, 256);
        k_gemm_mfma<1, 0><<<dim3(16, 80), 256, 0, stream>>>(
            u, Ft1 + (size_t)l * 262144, c1 + l * DFF, c1, c1, hbuf, hbuf, M, 1024, 256);
        k_gemm_ln16<<<M / 16, 256, 0, stream>>>(
            hbuf, Ft2 + (size_t)l * 262144, c2 + l * DM, ln2s + l * DM, ln2b + l * DM, u, 1024);
    }

    k_head<<<dim3(TGT / 16, 20), 256, 0, stream>>>(u, WhT2, scalef, out);
}

// Round 7
// 440.026 us; speedup vs baseline: 8.2850x; 1.0031x over previous
//
#include <hip/hip_runtime.h>
#include <math.h>

typedef unsigned short ushort;
typedef unsigned int uint;
typedef __attribute__((ext_vector_type(8))) short short8;
typedef __attribute__((ext_vector_type(4))) float f32x4;
typedef __attribute__((ext_vector_type(4))) ushort us4;

constexpr int BS = 2, C_IN = 8, CTX = 1024, TGT = 96;
constexpr int DM = 256, NH = 16, DFF = 1024, NL = 4;
constexpr int NF = 256, TOTAL = 320;
constexpr int NB = 16;
constexpr int DK = 16;
constexpr float EPS = 1e-5f;
constexpr float SCALE = 0.25f;
constexpr int KHEAD = DM * TOTAL;  // 81920
constexpr int M = NB * TOTAL;      // 5120

__device__ __forceinline__ ushort f2b(float x) {
    uint u = __float_as_uint(x);
    u += 0x7fff + ((u >> 16) & 1);
    return (ushort)(u >> 16);
}
__device__ __forceinline__ float bu2f(ushort x) { return __uint_as_float(((uint)x) << 16); }
__device__ __forceinline__ uint pack2(float a, float b) { return (uint)f2b(a) | ((uint)f2b(b) << 16); }

typedef __attribute__((address_space(3))) uint lds_u32;
typedef const __attribute__((address_space(1))) uint glb_u32;
__device__ __forceinline__ void ldst16(const void* g, void* l) {
    __builtin_amdgcn_global_load_lds((glb_u32*)g, (lds_u32*)l, 16, 0, 0);
}

// counted-vmcnt pipeline primitives: NEVER vmcnt(0) in the main loop (T4).
#define WAITV(n) asm volatile("s_waitcnt vmcnt(" #n ")" ::: "memory")
#define SBAR()   asm volatile("s_barrier" ::: "memory")
#define SBARW()  asm volatile("s_waitcnt lgkmcnt(0)\n\ts_barrier" ::: "memory")

// ---------------- prep v2: vectorized weight transposes + RevIN + embed + out-init ----------------
__global__ __launch_bounds__(256) void k_prep(
        const float* __restrict__ WQ, const float* __restrict__ WK,
        const float* __restrict__ WV, const float* __restrict__ WO,
        const float* __restrict__ F1, const float* __restrict__ F2,
        const float* __restrict__ Wh,
        ushort* __restrict__ Wtqkv, ushort* __restrict__ WtO,
        ushort* __restrict__ Ft1, ushort* __restrict__ Ft2,
        ushort* __restrict__ WhT2,
        const float* __restrict__ z, const float* __restrict__ rw,
        const float* __restrict__ rb,
        const float* __restrict__ Wf, const float* __restrict__ bfv,
        const float* __restrict__ Wc, const float* __restrict__ bcv,
        const float* __restrict__ Wpos, ushort* __restrict__ u,
        const float* __restrict__ bhv, float* __restrict__ outp,
        float* __restrict__ scalef) {
    __shared__ __align__(16) ushort tile[64 * 98];
    __shared__ float szn[CTX];
    __shared__ float red1[4], red2[4];
    int i = blockIdx.x, tid = threadIdx.x;

    if (i < 768) {
        const float* src; ushort* dst; int lsrc, ldst_, r0, c0;
        if (i < 256) {
            int mat = i >> 4, l = mat >> 2, w = mat & 3;
            src = (w == 0 ? WQ : (w == 1 ? WK : (w == 2 ? WV : WO))) + l * 65536;
            dst = (w < 3) ? (Wtqkv + (size_t)l * 768 * 256 + w * 65536)
                          : (WtO + (size_t)l * 65536);
            lsrc = 256; ldst_ = 256; r0 = ((i >> 2) & 3) * 64; c0 = (i & 3) * 64;
        } else if (i < 512) {
            int j = i - 256, l = j >> 6, t = j & 63;
            src = F1 + (size_t)l * 262144; dst = Ft1 + (size_t)l * 262144;
            lsrc = 1024; ldst_ = 256; r0 = (t >> 4) * 64; c0 = (t & 15) * 64;
        } else {
            int j = i - 512, l = j >> 6, t = j & 63;
            src = F2 + (size_t)l * 262144; dst = Ft2 + (size_t)l * 262144;
            lsrc = 256; ldst_ = 1024; r0 = (t >> 2) * 64; c0 = (t & 3) * 64;
        }
#pragma unroll
        for (int it = 0; it < 4; it++) {
            int fid = it * 256 + tid;
            int fr = fid >> 4, fc = fid & 15;
            f32x4 v = *(const f32x4*)&src[(size_t)(r0 + fr) * lsrc + c0 + fc * 4];
            ushort* tr = &tile[fr * 66];
            tr[fc * 4 + 0] = f2b(v[0]); tr[fc * 4 + 1] = f2b(v[1]);
            tr[fc * 4 + 2] = f2b(v[2]); tr[fc * 4 + 3] = f2b(v[3]);
        }
        __syncthreads();
#pragma unroll
        for (int it = 0; it < 4; it++) {
            int sid = it * 256 + tid;
            int cr = sid >> 4, cc = sid & 15;
            us4 v = (us4){ tile[(cc * 4 + 0) * 66 + cr], tile[(cc * 4 + 1) * 66 + cr],
                           tile[(cc * 4 + 2) * 66 + cr], tile[(cc * 4 + 3) * 66 + cr] };
            *(us4*)&dst[(size_t)(c0 + cr) * ldst_ + r0 + cc * 4] = v;
        }
    } else if (i < 2048) {
        int j = i - 768;
        int pp = j >> 2, d0 = (j & 3) * 64;
#pragma unroll
        for (int it = 0; it < 6; it++) {
            int fid = it * 256 + tid;
            int fr = fid / 24, fc = fid % 24;
            f32x4 v = *(const f32x4*)&Wh[((size_t)(d0 + fr) * 320 + pp) * 96 + fc * 4];
            ushort* tr = &tile[fr * 98];
            tr[fc * 4 + 0] = f2b(v[0]); tr[fc * 4 + 1] = f2b(v[1]);
            tr[fc * 4 + 2] = f2b(v[2]); tr[fc * 4 + 3] = f2b(v[3]);
        }
        __syncthreads();
#pragma unroll
        for (int it = 0; it < 6; it++) {
            int sid = it * 256 + tid;
            int tr = sid >> 4, dc = sid & 15;
            us4 v = (us4){ tile[(dc * 4 + 0) * 98 + tr], tile[(dc * 4 + 1) * 98 + tr],
                           tile[(dc * 4 + 2) * 98 + tr], tile[(dc * 4 + 3) * 98 + tr] };
            *(us4*)&WhT2[(size_t)tr * KHEAD + pp * 256 + d0 + dc * 4] = v;
        }
    } else {
        int j = i - 2048;
        int bc = j / 80, pb = j % 80;
        int wave = tid >> 6, lane = tid & 63;
        f32x4 zv = *(const f32x4*)&z[bc * CTX + tid * 4];
        float s1 = zv[0] + zv[1] + zv[2] + zv[3];
        float s2 = zv[0] * zv[0] + zv[1] * zv[1] + zv[2] * zv[2] + zv[3] * zv[3];
#pragma unroll
        for (int off = 1; off < 64; off <<= 1) {
            s1 += __shfl_xor(s1, off);
            s2 += __shfl_xor(s2, off);
        }
        if (lane == 0) { red1[wave] = s1; red2[wave] = s2; }
        __syncthreads();
        s1 = red1[0] + red1[1] + red1[2] + red1[3];
        s2 = red2[0] + red2[1] + red2[2] + red2[3];
        float m = s1 * (1.0f / CTX);
        float var = s2 * (1.0f / CTX) - m * m;
        float sd = sqrtf(var + EPS);
        int c = bc & 7;
        float w = rw[c], bb = rb[c];
        float inv_sd_w = w / sd;
#pragma unroll
        for (int k = 0; k < 4; k++) szn[tid * 4 + k] = (zv[k] - m) * inv_sd_w + bb;
        if (pb == 0) {
            if (tid < TGT) outp[bc * TGT + tid] = (bhv[tid] - bb) / (w + EPS * EPS) * sd + m;
            if (tid == 0) scalef[bc] = sd / (w + EPS * EPS);
        }
        __syncthreads();
#pragma unroll
        for (int pi = 0; pi < 4; pi++) {
            int p = pb * 4 + pi, d = tid;
            float acc;
            if (p < NF) {
                acc = bfv[d];
                int base = p * 4;
#pragma unroll
                for (int q = 0; q < 8; q++)
                    acc += szn[min(base + q, CTX - 1)] * Wf[q * DM + d];
            } else {
                acc = bcv[d];
                int base = (p - NF) * 16;
#pragma unroll
                for (int q = 0; q < 32; q++)
                    acc += szn[min(base + q, CTX - 1)] * Wc[q * DM + d];
            }
            acc += Wpos[p * DM + d];
            u[((size_t)bc * TOTAL + p) * DM + d] = f2b(acc);
        }
    }
}

// ---------------- bf16 MFMA GEMM, 64x64 tile, DEPTH-3 counted-vmcnt pipeline ----------------
// 2 loads/step/wave -> steady wait vmcnt(4); epilogue 2 -> 0.
template <int GELU, int QKV>
__global__ __launch_bounds__(256) void k_gemm_mfma(const ushort* __restrict__ A,
                                                   const ushort* __restrict__ Wt,
                                                   const float* __restrict__ b0,
                                                   const float* __restrict__ b1,
                                                   const float* __restrict__ b2,
                                                   ushort* __restrict__ C,
                                                   ushort* __restrict__ C2,
                                                   int Mm, int N, int K) {
    __shared__ ushort As[3][64][32];
    __shared__ ushort Bs[3][64][32];
    int tid = threadIdx.x;
    int wave = tid >> 6, lane = tid & 63;
    int quad = lane >> 4, l16 = lane & 15;
    int m0 = blockIdx.y * 64, n0 = blockIdx.x * 64;

    f32x4 acc[4];
#pragma unroll
    for (int nt = 0; nt < 4; nt++) acc[nt] = (f32x4){0.f, 0.f, 0.f, 0.f};

    int srow = wave * 16 + (lane >> 2);
    int sc = (lane & 3) ^ ((srow >> 1) & 3);
    const ushort* Ag = &A[(size_t)(m0 + srow) * K + sc * 8];
    const ushort* Bg = &Wt[(size_t)(n0 + srow) * K + sc * 8];
    int rchunk = (quad ^ ((l16 >> 1) & 3)) * 8;

    int nstep = K >> 5;  // >= 8 for all call sites
    ldst16(Ag,      &As[0][wave * 16][0]);
    ldst16(Bg,      &Bs[0][wave * 16][0]);
    ldst16(Ag + 32, &As[1][wave * 16][0]);
    ldst16(Bg + 32, &Bs[1][wave * 16][0]);
    ldst16(Ag + 64, &As[2][wave * 16][0]);
    ldst16(Bg + 64, &Bs[2][wave * 16][0]);

    int cur = 0;
    for (int t = 0; t < nstep; t++) {
        if (t < nstep - 2) WAITV(4);
        else if (t == nstep - 2) WAITV(2);
        else WAITV(0);
        SBAR();
        short8 af = *(const short8*)&As[cur][wave * 16 + l16][rchunk];
#pragma unroll
        for (int nt = 0; nt < 4; nt++) {
            short8 bf = *(const short8*)&Bs[cur][nt * 16 + l16][rchunk];
            acc[nt] = __builtin_amdgcn_mfma_f32_16x16x32_bf16(af, bf, acc[nt], 0, 0, 0);
        }
        if (t + 3 < nstep) {
            SBARW();   // readers done with buf cur before its DMA overwrite is issued
            ldst16(Ag + (t + 3) * 32, &As[cur][wave * 16][0]);
            ldst16(Bg + (t + 3) * 32, &Bs[cur][wave * 16][0]);
        }
        cur = (cur == 2) ? 0 : cur + 1;
    }
#pragma unroll
    for (int nt = 0; nt < 4; nt++) {
        int col = n0 + nt * 16 + l16;
        float bi;
        if (QKV) {
            int bs = (n0 + nt * 16) >> 8;
            const float* bp = bs == 0 ? b0 : (bs == 1 ? b1 : b2);
            bi = bp[col & 255];
        } else {
            bi = b0[col];
        }
#pragma unroll
        for (int r = 0; r < 4; r++) {
            int rowm = m0 + wave * 16 + quad * 4 + r;
            float vv = acc[nt][r] + bi;
            if (GELU) vv = vv * 0.5f * (1.0f + erff(vv * 0.70710678118f));
            if (QKV) {
                int bs = col >> 8;
                ushort* dst = (bs == 2) ? (C2 + (size_t)rowm * DM)
                                        : (C + (size_t)bs * (M * DM) + (size_t)rowm * DM);
                dst[col & 255] = f2b(vv);
            } else {
                C[(size_t)rowm * N + col] = f2b(vv);
            }
        }
    }
}

// ---------------- GEMM(16x256)+bias+residual+LN, DEPTH-3 counted-vmcnt pipeline ----------------
// wave0: 5 loads/step (A+4B) -> steady vmcnt(10); waves1-3: 4/step -> vmcnt(8). Epilogue 5/4 -> 0.
__global__ __launch_bounds__(256) void k_gemm_ln16(const ushort* __restrict__ A,
                                                   const ushort* __restrict__ Wt,
                                                   const float* __restrict__ bias,
                                                   const float* __restrict__ ls,
                                                   const float* __restrict__ lb,
                                                   ushort* __restrict__ u, int K) {
    __shared__ ushort As[3][16][32];
    __shared__ ushort Bs[3][256][32];
    __shared__ float ps1[16][4], ps2[16][4];
    int tid = threadIdx.x;
    int wave = tid >> 6, lane = tid & 63;
    int quad = lane >> 4, l16 = lane & 15;
    int m0 = blockIdx.x * 16;

    f32x4 acc[4];
#pragma unroll
    for (int nt = 0; nt < 4; nt++) acc[nt] = (f32x4){0.f, 0.f, 0.f, 0.f};

    int brow = wave * 16 + (lane >> 2);
    int bc_swz = (lane & 3) ^ ((brow >> 1) & 3);
    const ushort* Bg0 = &Wt[(size_t)brow * K + bc_swz * 8];
    int ar = lane >> 2;
    int ac = (lane & 3) ^ ((ar >> 1) & 3);
    const ushort* Ag = &A[(size_t)(m0 + ar) * K + ac * 8];
    int rchunk = (quad ^ ((l16 >> 1) & 3)) * 8;

    int nstep = K >> 5;  // 8 or 32
    // prologue: 3 steps in flight
    if (tid < 64) ldst16(Ag, &As[0][0][0]);
#pragma unroll
    for (int i = 0; i < 4; i++) ldst16(Bg0 + (size_t)i * 64 * K, &Bs[0][i * 64 + wave * 16][0]);
    if (tid < 64) ldst16(Ag + 32, &As[1][0][0]);
#pragma unroll
    for (int i = 0; i < 4; i++) ldst16(Bg0 + (size_t)i * 64 * K + 32, &Bs[1][i * 64 + wave * 16][0]);
    if (tid < 64) ldst16(Ag + 64, &As[2][0][0]);
#pragma unroll
    for (int i = 0; i < 4; i++) ldst16(Bg0 + (size_t)i * 64 * K + 64, &Bs[2][i * 64 + wave * 16][0]);

    int cur = 0;
    for (int t = 0; t < nstep; t++) {
        if (t < nstep - 2) {
            if (wave == 0) WAITV(10); else WAITV(8);
        } else if (t == nstep - 2) {
            if (wave == 0) WAITV(5); else WAITV(4);
        } else {
            WAITV(0);
        }
        SBAR();
        short8 af = *(const short8*)&As[cur][l16][rchunk];
#pragma unroll
        for (int nt = 0; nt < 4; nt++) {
            short8 bf = *(const short8*)&Bs[cur][wave * 64 + nt * 16 + l16][rchunk];
            acc[nt] = __builtin_amdgcn_mfma_f32_16x16x32_bf16(af, bf, acc[nt], 0, 0, 0);
        }
        if (t + 3 < nstep) {
            SBARW();
            if (tid < 64) ldst16(Ag + (t + 3) * 32, &As[cur][0][0]);
#pragma unroll
            for (int i = 0; i < 4; i++)
                ldst16(Bg0 + (size_t)i * 64 * K + (t + 3) * 32, &Bs[cur][i * 64 + wave * 16][0]);
        }
        cur = (cur == 2) ? 0 : cur + 1;
    }
    float xv[4][4];
#pragma unroll
    for (int r = 0; r < 4; r++) {
        int rowg = m0 + quad * 4 + r;
        float s1 = 0.f, s2 = 0.f;
#pragma unroll
        for (int nt = 0; nt < 4; nt++) {
            int col = wave * 64 + nt * 16 + l16;
            float x = acc[nt][r] + bias[col] + bu2f(u[(size_t)rowg * DM + col]);
            xv[r][nt] = x; s1 += x; s2 += x * x;
        }
        s1 += __shfl_xor(s1, 1); s2 += __shfl_xor(s2, 1);
        s1 += __shfl_xor(s1, 2); s2 += __shfl_xor(s2, 2);
        s1 += __shfl_xor(s1, 4); s2 += __shfl_xor(s2, 4);
        s1 += __shfl_xor(s1, 8); s2 += __shfl_xor(s2, 8);
        if (l16 == 0) { ps1[quad * 4 + r][wave] = s1; ps2[quad * 4 + r][wave] = s2; }
    }
    __syncthreads();
#pragma unroll
    for (int r = 0; r < 4; r++) {
        int rowl = quad * 4 + r, rowg = m0 + rowl;
        float s1 = ps1[rowl][0] + ps1[rowl][1] + ps1[rowl][2] + ps1[rowl][3];
        float s2 = ps2[rowl][0] + ps2[rowl][1] + ps2[rowl][2] + ps2[rowl][3];
        float m = s1 * (1.0f / DM);
        float var = s2 * (1.0f / DM) - m * m;
        float rs = rsqrtf(var + EPS);
#pragma unroll
        for (int nt = 0; nt < 4; nt++) {
            int col = wave * 64 + nt * 16 + l16;
            u[(size_t)rowg * DM + col] = f2b((xv[r][nt] - m) * rs * ls[col] + lb[col]);
        }
    }
}

// ---------------- MFMA fused attention: residual scores recomputed; K double-buffered ----------------
__global__ __launch_bounds__(256, 4) void k_attn(const ushort* __restrict__ qk, const ushort* __restrict__ vm,
                                                 ushort* __restrict__ ao, int nj) {
    __shared__ ushort sh[15360];
    uint* sh32 = (uint*)sh;
    int bh = blockIdx.x, b = bh >> 4, h = bh & 15;
    int i0 = blockIdx.y * 64;
    int t = threadIdx.x, wave = t >> 6, lane = t & 63, quad = lane >> 4, l16 = lane & 15;
    const short8 zero8 = (short8){0, 0, 0, 0, 0, 0, 0, 0};

    f32x4 acc[20];
#pragma unroll
    for (int nt = 0; nt < 20; nt++) acc[nt] = (f32x4){0.f, 0.f, 0.f, 0.f};

    for (int idx = t; idx < 320; idx += 256) {
        int jp = idx >> 1, dh = idx & 1;
        int j = jp * 2;
        uint4 a = *(const uint4*)&vm[((size_t)b * TOTAL + j) * DM + h * DK + dh * 8];
        uint4 bb = *(const uint4*)&vm[((size_t)b * TOTAL + j + 1) * DM + h * DK + dh * 8];
        const ushort* ap = (const ushort*)&a;
        const ushort* bp = (const ushort*)&bb;
        int jr = j & 31;
        int q = (jr & 15) >> 2, jj = ((jr >> 4) << 2) + (jr & 3);
        int base = 10240 + ((j >> 5) * 4 + q) * 128 + jj;
#pragma unroll
        for (int dd = 0; dd < 8; dd++) {
            int d = dh * 8 + dd;
            uint val = (uint)ap[dd] | ((uint)bp[dd] << 16);
            sh32[(base + d * 8) >> 1] = val;
        }
    }

    for (int jl = 0; jl < nj; jl++) {
        const ushort* qm = qk + (size_t)(2 * jl) * M * DM;
        const ushort* km = qm + (size_t)M * DM;
        int kb = (jl & 1) * 5120;
        for (int idx = t; idx < 640; idx += 256) {
            int j = idx >> 1, half = idx & 1;
            short8 kv = *(const short8*)&km[((size_t)b * TOTAL + j) * DM + h * DK + half * 8];
            int jt = j >> 4, jln = j & 15;
            *(short8*)&sh[kb + ((jt * 2 + half) * 16 + jln) * 8] = kv;
        }
        short8 qf = zero8;
        if (quad < 2) qf = *(const short8*)&qm[((size_t)b * TOTAL + i0 + wave * 16 + l16) * DM + h * DK + quad * 8];
        __syncthreads();
#pragma unroll
        for (int nt = 0; nt < 20; nt++) {
            short8 kf = *(const short8*)&sh[kb + ((nt * 2 + (quad & 1)) * 16 + l16) * 8];
            acc[nt] = __builtin_amdgcn_mfma_f32_16x16x32_bf16(kf, qf, acc[nt], 0, 0, 0);
        }
    }

    float mx = -1e30f;
#pragma unroll
    for (int nt = 0; nt < 20; nt++)
#pragma unroll
        for (int r = 0; r < 4; r++) { acc[nt][r] *= SCALE; mx = fmaxf(mx, acc[nt][r]); }
    mx = fmaxf(mx, __shfl_xor(mx, 16));
    mx = fmaxf(mx, __shfl_xor(mx, 32));
    float sum = 0.f;
#pragma unroll
    for (int nt = 0; nt < 20; nt++)
#pragma unroll
        for (int r = 0; r < 4; r++) { acc[nt][r] = __expf(acc[nt][r] - mx); sum += acc[nt][r]; }
    sum += __shfl_xor(sum, 16);
    sum += __shfl_xor(sum, 32);
    float inv = 1.f / sum;
#pragma unroll
    for (int nt = 0; nt < 20; nt++)
#pragma unroll
        for (int r = 0; r < 4; r++) acc[nt][r] *= inv;

    f32x4 oacc = (f32x4){0.f, 0.f, 0.f, 0.f};
#pragma unroll
    for (int jt2 = 0; jt2 < 10; jt2++) {
        short8 vt = *(const short8*)&sh[10240 + ((jt2 * 4 + quad) * 16 + l16) * 8];
        union { short8 v; uint u[4]; } pf;
        pf.u[0] = pack2(acc[2 * jt2][0], acc[2 * jt2][1]);
        pf.u[1] = pack2(acc[2 * jt2][2], acc[2 * jt2][3]);
        pf.u[2] = pack2(acc[2 * jt2 + 1][0], acc[2 * jt2 + 1][1]);
        pf.u[3] = pack2(acc[2 * jt2 + 1][2], acc[2 * jt2 + 1][3]);
        oacc = __builtin_amdgcn_mfma_f32_16x16x32_bf16(vt, pf.v, oacc, 0, 0, 0);
    }
    us4 ov4 = (us4){f2b(oacc[0]), f2b(oacc[1]), f2b(oacc[2]), f2b(oacc[3])};
    *(us4*)&ao[((size_t)b * TOTAL + i0 + wave * 16 + l16) * DM + h * DK + quad * 4] = ov4;
}

// ---------------- head GEMM: MFMA split-K, atomic accumulate into pre-initialized out ----------------
__global__ __launch_bounds__(256) void k_head(const ushort* __restrict__ u, const ushort* __restrict__ WhT2,
                                              const float* __restrict__ scalef, float* __restrict__ out) {
    int t0 = blockIdx.x * 16;
    int wave = threadIdx.x >> 6, lane = threadIdx.x & 63;
    int quad = lane >> 4, l16 = lane & 15;
    int chunk = blockIdx.y * 4 + wave;
    int kbeg = chunk * 1024;
    f32x4 acc = (f32x4){0.f, 0.f, 0.f, 0.f};
    const ushort* za = &u[(size_t)l16 * KHEAD + quad * 8];
    const ushort* wb = &WhT2[(size_t)(t0 + l16) * KHEAD + quad * 8];
#pragma unroll 4
    for (int k = kbeg; k < kbeg + 1024; k += 32) {
        short8 af = *(const short8*)&za[k];
        short8 bf = *(const short8*)&wb[k];
        acc = __builtin_amdgcn_mfma_f32_16x16x32_bf16(af, bf, acc, 0, 0, 0);
    }
#pragma unroll
    for (int r = 0; r < 4; r++) {
        int bcr = quad * 4 + r;
        atomicAdd(&out[bcr * TGT + t0 + l16], acc[r] * scalef[bcr]);
    }
}

extern "C" void kernel_launch(void* const* d_in, const int* in_sizes, int n_in,
                              void* d_out, int out_size, void* d_ws, size_t ws_size,
                              hipStream_t stream) {
    const float* z       = (const float*)d_in[0];
    const float* revin_w = (const float*)d_in[1];
    const float* revin_b = (const float*)d_in[2];
    const float* Wf      = (const float*)d_in[3];
    const float* bfv     = (const float*)d_in[4];
    const float* Wc      = (const float*)d_in[5];
    const float* bcv     = (const float*)d_in[6];
    const float* Wpos    = (const float*)d_in[7];
    const float* WQ      = (const float*)d_in[8];
    const float* bQ      = (const float*)d_in[9];
    const float* WK      = (const float*)d_in[10];
    const float* bK      = (const float*)d_in[11];
    const float* WV      = (const float*)d_in[12];
    const float* bV      = (const float*)d_in[13];
    const float* WO      = (const float*)d_in[14];
    const float* bO      = (const float*)d_in[15];
    const float* ln1s    = (const float*)d_in[16];
    const float* ln1b    = (const float*)d_in[17];
    const float* ln2s    = (const float*)d_in[18];
    const float* ln2b    = (const float*)d_in[19];
    const float* F1      = (const float*)d_in[20];
    const float* c1      = (const float*)d_in[21];
    const float* F2      = (const float*)d_in[22];
    const float* c2      = (const float*)d_in[23];
    const float* Wh      = (const float*)d_in[24];
    const float* bh      = (const float*)d_in[25];
    float* out = (float*)d_out;

    char* p = (char*)d_ws;
    float* scalef = (float*)p;   p += 16 * 4;
    p = (char*)(((size_t)p + 255) & ~255ull);
    ushort* u     = (ushort*)p;  p += (size_t)M * DM * 2;
    ushort* qkbuf = (ushort*)p;  p += (size_t)NL * 2 * M * DM * 2;   // per-layer [Q_l, K_l]
    ushort* vbuf  = (ushort*)p;  p += (size_t)M * DM * 2;
    ushort* ax    = (ushort*)p;  p += (size_t)M * DM * 2;
    ushort* hbuf  = (ushort*)p;  p += (size_t)M * DFF * 2;
    ushort* Wtqkv = (ushort*)p;  p += (size_t)NL * 768 * 256 * 2;
    ushort* WtO   = (ushort*)p;  p += (size_t)NL * 256 * 256 * 2;
    ushort* Ft1   = (ushort*)p;  p += (size_t)NL * 1024 * 256 * 2;
    ushort* Ft2   = (ushort*)p;  p += (size_t)NL * 256 * 1024 * 2;
    ushort* WhT2  = (ushort*)p;  p += (size_t)TGT * KHEAD * 2;

    k_prep<<<3328, 256, 0, stream>>>(WQ, WK, WV, WO, F1, F2, Wh,
                                     Wtqkv, WtO, Ft1, Ft2, WhT2,
                                     z, revin_w, revin_b,
                                     Wf, bfv, Wc, bcv, Wpos, u,
                                     bh, out, scalef);

    for (int l = 0; l < NL; l++) {
        k_gemm_mfma<0, 1><<<dim3(12, 80), 256, 0, stream>>>(
            u, Wtqkv + (size_t)l * 768 * 256, bQ + l * DM, bK + l * DM, bV + l * DM,
            qkbuf + (size_t)l * 2 * M * DM, vbuf, M, 768, 256);
        k_attn<<<dim3(NB * NH, 5), 256, 0, stream>>>(qkbuf, vbuf, ax, l + 1);
        k_gemm_ln16<<<M / 16, 256, 0, stream>>>(
            ax, WtO + (size_t)l * 65536, bO + l * DM, ln1s + l * DM, ln1b + l * DM, u, 256);
        k_gemm_mfma<1, 0><<<dim3(16, 80), 256, 0, stream>>>(
            u, Ft1 + (size_t)l * 262144, c1 + l * DFF, c1, c1, hbuf, hbuf, M, 1024, 256);
        k_gemm_ln16<<<M / 16, 256, 0, stream>>>(
            hbuf, Ft2 + (size_t)l * 262144, c2 + l * DM, ln2s + l * DM, ln2b + l * DM, u, 1024);
    }

    k_head<<<dim3(TGT / 16, 20), 256, 0, stream>>>(u, WhT2, scalef, out);
}